// Round 6
// baseline (3216.532 us; speedup 1.0000x reference)
//
#include <hip/hip_runtime.h>

#define B_ 16
#define N_ 1024
#define M_ 4096
#define D_ 64
#define SROWS_ (N_ + 63)   // skewed rows per 256-col tile: 1087
#define BTQ_ 96            // backtrack window quads (384 cells)

__device__ __forceinline__ float finf() { return __builtin_inff(); }

// wave-wide shift right by 1 lane; lane 0 gets old (0), always select-overridden.
__device__ __forceinline__ float wave_shr1(float x) {
  return __int_as_float(__builtin_amdgcn_update_dpp(
      0, __float_as_int(x), 0x138, 0xF, 0xF, false));
}
__device__ __forceinline__ float rdlane(float v, int l) {
  return __int_as_float(__builtin_amdgcn_readlane(__float_as_int(v), l));
}

// ---------------------------------------------------------------------------
__global__ void prep_kernel(const float* __restrict__ x,
                            const float* __restrict__ x_t,
                            float* __restrict__ x2,
                            float* __restrict__ w_ts_out) {
  int id = blockIdx.x * blockDim.x + threadIdx.x;
  const float4* xr = (const float4*)(x + (size_t)id * D_);
  float s = 0.f;
#pragma unroll
  for (int e = 0; e < D_ / 4; ++e) {
    float4 v = xr[e];
    s += v.x * v.x + v.y * v.y + v.z * v.z + v.w * v.w;
  }
  x2[id] = s;
  w_ts_out[id] = x_t[id];
}

// ---------------------------------------------------------------------------
// GEMM writing C pre-skewed per 256-col tile: Cs[tile][(i+l)*256 + ct], l=ct>>2.
// ---------------------------------------------------------------------------
__global__ __launch_bounds__(256) void gemm_kernel(
    const float* __restrict__ x, const float* __restrict__ y,
    const float* __restrict__ x2, float* __restrict__ Cs,
    int chunkBase) {
  const int b = blockIdx.z;
  const int tile = blockIdx.x;
  const int lane = threadIdx.x & 63;
  const int wid = threadIdx.x >> 6;
  const int ct = wid * 64 + lane;
  const int j = chunkBase + tile * 256 + ct;
  const int l = ct >> 2;
  float* CsT = Cs + (size_t)(b * 4 + tile) * SROWS_ * 256;

  const float4* yrow = (const float4*)(y + ((size_t)b * M_ + j) * D_);
  float4 yr[D_ / 4];
#pragma unroll
  for (int e = 0; e < D_ / 4; ++e) yr[e] = yrow[e];
  float y2 = 0.f;
#pragma unroll
  for (int e = 0; e < D_ / 4; ++e)
    y2 += yr[e].x * yr[e].x + yr[e].y * yr[e].y + yr[e].z * yr[e].z + yr[e].w * yr[e].w;

  const int ibeg = blockIdx.y * 128;
  for (int i = ibeg; i < ibeg + 128; ++i) {
    const float4* xr = (const float4*)(x + ((size_t)b * N_ + i) * D_);
    float acc = 0.f;
#pragma unroll
    for (int e = 0; e < D_ / 4; ++e) {
      float4 xv = xr[e];
      acc += xv.x * yr[e].x + xv.y * yr[e].y + xv.z * yr[e].z + xv.w * yr[e].w;
    }
    CsT[(size_t)(i + l) * 256 + ct] = x2[b * N_ + i] + y2 - 2.f * acc;
  }
}

// ---------------------------------------------------------------------------
// Systolic DP, 4 batches per 1024-thread workgroup (4 waves/SIMD co-resident
// for latency hiding). Group g = batch; wave W in group owns a 256-col tile;
// lane l owns 4 cols; step s => row i = s - lane. Slimmed step: uniform SGPR
// base pointers (readfirstlane + scalar increment), per-block edge ds_read +
// per-step v_readlane, peeled row0/fin phases, s_sleep spin loops.
// ---------------------------------------------------------------------------
__global__ __launch_bounds__(1024) void dtw_dp4(
    const float* __restrict__ Cs, unsigned char* __restrict__ dec,
    const float* __restrict__ carryIn, float* __restrict__ carryOut,
    float* __restrict__ partV, int* __restrict__ partJ,
    int chunk, int hasCarry) {
  const int t = threadIdx.x;
  const int g = t >> 8;
  const int lane = t & 63;
  const int W = (t >> 6) & 3;
  const int b = blockIdx.x * 4 + g;
  const int tl = t & 255;

  __shared__ float eRing[4][192];
  __shared__ int eProg[4][4];
  __shared__ int eCons[4][5];
  __shared__ float cring[4][256];
  __shared__ float redV[4][4];
  __shared__ int redJ[4][4];

  if (tl < 3) eProg[g][tl] = -1;
  if (tl < 5) eCons[g][tl] = 0;
  const float* cIn2 = carryIn + b * N_;
  if (W == 0 && hasCarry) {
    cring[g][lane] = cIn2[lane];
    cring[g][lane + 64] = cIn2[lane + 64];
    cring[g][lane + 128] = cIn2[lane + 128];
  }
  __syncthreads();

  const bool isProd = (W < 3);
  const bool isCons = (W > 0);
  const bool doCarry = (W == 3) && (chunk < 3);

  volatile float* ringW = &eRing[g][W * 64];       // deref only if isProd
  const float* ringR = &eRing[g][(W - 1) * 64];    // deref only if isCons
  volatile int* flagW = &eProg[g][W];
  volatile int* progR = &eProg[g][W - 1 < 0 ? 0 : W - 1];
  volatile int* consW = &eCons[g][W];
  volatile int* consR = &eCons[g][W + 1];

  const int tileG = chunk * 4 + W;
  unsigned char* decBase =
      dec + (size_t)__builtin_amdgcn_readfirstlane(b * 16 + tileG) *
                ((size_t)SROWS_ * 64);
  const float* loadP =
      Cs + (size_t)__builtin_amdgcn_readfirstlane(b * 4 + W) *
               ((size_t)SROWS_ * 256);
  float* carryB = carryOut + __builtin_amdgcn_readfirstlane(b) * N_;
  const int jbase = tileG * 256 + lane * 4;

  float4 cc0 = ((const float4*)(loadP + 0 * 256))[lane];
  float4 cc1 = ((const float4*)(loadP + 1 * 256))[lane];
  float4 cc2 = ((const float4*)(loadP + 2 * 256))[lane];
  float4 cc3 = ((const float4*)(loadP + 3 * 256))[lane];
  float4 cc4 = ((const float4*)(loadP + 4 * 256))[lane];
  float4 cc5 = ((const float4*)(loadP + 5 * 256))[lane];
  float4 cc6 = ((const float4*)(loadP + 6 * 256))[lane];
  float4 cc7 = ((const float4*)(loadP + 7 * 256))[lane];
  loadP += 8 * 256;

  const float INF = finf();
  float edgeVec = INF, edgePrev = INF;
  float up0 = 0.f, up1 = 0.f, up2 = 0.f, up3 = 0.f;
  float dpp1 = INF, dpp2 = INF;
  float fin0 = INF, fin1 = INF, fin2 = INF, fin3 = INF;

#define BLOCKHEAD()                                                           \
  {                                                                           \
    if (isCons) {                                                             \
      if (sb < N_) {                                                          \
        if (lane == 0) *consW = sb;                                           \
        const int tgt = (sb + 7 < N_) ? sb + 7 : N_ - 1;                      \
        while (*progR < tgt) __builtin_amdgcn_s_sleep(1);                     \
        asm volatile("" ::: "memory");                                        \
        edgePrev = rdlane(edgeVec, 7);                                        \
        edgeVec = ringR[(sb + lane) & 63];                                    \
      }                                                                       \
    } else if (hasCarry) {                                                    \
      if ((sb & 63) == 0 && sb >= 64) {                                       \
        const int r = sb + 128 + lane;                                        \
        if (r < N_) cring[g][r & 255] = cIn2[r];                              \
      }                                                                       \
      edgePrev = rdlane(edgeVec, 7);                                          \
      if (sb < N_) edgeVec = cring[g][(sb + lane) & 255];                     \
    }                                                                         \
  }

#define DPSTEP(KK, CCV, ROW0, FIN)                                            \
  {                                                                           \
    const int s = sb + (KK);                                                  \
    const float lv = rdlane(edgeVec, (KK));                                   \
    const float lvm1 =                                                        \
        (KK) ? rdlane(edgeVec, ((KK) > 0 ? (KK) - 1 : 0)) : edgePrev;         \
    const float left = (lane == 0) ? lv : dpp1;                               \
    const float diag = (lane == 0) ? lvm1 : dpp2;                             \
    float m0 = fminf(up0, left);                                              \
    float bv0 = fminf(diag, m0);                                              \
    unsigned int pk = (diag <= m0) ? 0u : ((up0 <= left) ? 1u : 2u);          \
    if (ROW0) bv0 = (s == lane) ? 0.f : bv0;                                  \
    const float D0 = CCV.x + bv0;                                             \
    float m1 = fminf(up1, D0);                                                \
    float bv1 = fminf(up0, m1);                                               \
    pk |= ((up0 <= m1) ? 0u : ((up1 <= D0) ? 1u : 2u)) << 2;                  \
    if (ROW0) bv1 = (s == lane) ? 0.f : bv1;                                  \
    const float D1 = CCV.y + bv1;                                             \
    float m2 = fminf(up2, D1);                                                \
    float bv2 = fminf(up1, m2);                                               \
    pk |= ((up1 <= m2) ? 0u : ((up2 <= D1) ? 1u : 2u)) << 4;                  \
    if (ROW0) bv2 = (s == lane) ? 0.f : bv2;                                  \
    const float D2 = CCV.z + bv2;                                             \
    float m3 = fminf(up3, D2);                                                \
    float bv3 = fminf(up2, m3);                                               \
    pk |= ((up2 <= m3) ? 0u : ((up3 <= D2) ? 1u : 2u)) << 6;                  \
    if (ROW0) bv3 = (s == lane) ? 0.f : bv3;                                  \
    const float D3 = CCV.w + bv3;                                             \
    decBase[lane] = (unsigned char)pk;                                        \
    decBase += 64;                                                            \
    if (FIN) {                                                                \
      const bool lr = (s == 1023 + lane);                                     \
      fin0 = lr ? D0 : fin0; fin1 = lr ? D1 : fin1;                           \
      fin2 = lr ? D2 : fin2; fin3 = lr ? D3 : fin3;                           \
    }                                                                         \
    if (doCarry) {                                                            \
      if (lane == 63 && (unsigned)(s - 63) < (unsigned)N_)                    \
        carryB[s - 63] = D3;                                                  \
    }                                                                         \
    const float sh = wave_shr1(D3);                                           \
    dpp2 = dpp1; dpp1 = sh;                                                   \
    up0 = D0; up1 = D1; up2 = D2; up3 = D3;                                   \
    if (isProd) {                                                             \
      const int rp = s - 63;                                                  \
      if ((unsigned)rp < (unsigned)N_) {                                      \
        if (lane == 63) ringW[rp & 63] = D3;                                  \
        if ((rp & 7) == 7) {                                                  \
          asm volatile("" ::: "memory");                                      \
          __builtin_amdgcn_s_waitcnt(0xC07F);                                 \
          if (lane == 63) *flagW = rp;                                        \
          while (*consR < rp - 55) __builtin_amdgcn_s_sleep(1);               \
        }                                                                     \
      }                                                                       \
    }                                                                         \
    CCV = ((const float4*)loadP)[lane];                                       \
    loadP += 256;                                                             \
  }

#define STEP8(R0, FN)                                                         \
  DPSTEP(0, cc0, R0, FN) DPSTEP(1, cc1, R0, FN) DPSTEP(2, cc2, R0, FN)        \
  DPSTEP(3, cc3, R0, FN) DPSTEP(4, cc4, R0, FN) DPSTEP(5, cc5, R0, FN)        \
  DPSTEP(6, cc6, R0, FN) DPSTEP(7, cc7, R0, FN)

  int sb = 0;
  for (; sb < 64; sb += 8) {       // prologue: row0 selects live here
    BLOCKHEAD();
    STEP8(1, 0)
  }
  for (; sb < 1016; sb += 8) {     // main: no row0, no fin
    BLOCKHEAD();
    STEP8(0, 0)
  }
  for (; sb < 1088; sb += 8) {     // epilogue: fin captures (s = 1023+lane)
    BLOCKHEAD();
    STEP8(0, 1)
  }
#undef DPSTEP
#undef STEP8
#undef BLOCKHEAD

  float mv = fin0; int mj = jbase;
  if (fin1 < mv) { mv = fin1; mj = jbase + 1; }
  if (fin2 < mv) { mv = fin2; mj = jbase + 2; }
  if (fin3 < mv) { mv = fin3; mj = jbase + 3; }
#pragma unroll
  for (int off = 32; off > 0; off >>= 1) {
    const float ov = __shfl_down(mv, off);
    const int oj = __shfl_down(mj, off);
    if (ov < mv || (ov == mv && oj < mj)) { mv = ov; mj = oj; }
  }
  if (lane == 0) { redV[g][W] = mv; redJ[g][W] = mj; }
  __syncthreads();
  if (tl == 0) {
    float bm = redV[g][0]; int bj = redJ[g][0];
#pragma unroll
    for (int w = 1; w < 4; ++w)
      if (redV[g][w] < bm) { bm = redV[g][w]; bj = redJ[g][w]; }
    partV[b * 4 + chunk] = bm;
    partJ[b * 4 + chunk] = bj;
  }
}

// ---------------------------------------------------------------------------
// Backtrack over skewed dec (round-5 version, unchanged).
// ---------------------------------------------------------------------------
__global__ __launch_bounds__(64) void backtrack_kernel(
    const unsigned char* __restrict__ dec, const float* __restrict__ partV,
    const int* __restrict__ partJ, int nch, const float* __restrict__ y_t,
    float* __restrict__ w_vs, float* __restrict__ cost_out) {
  const int b = blockIdx.x;
  const int lane = threadIdx.x;
  __shared__ unsigned char win[64][BTQ_ + 4];
  __shared__ unsigned short tab[64][BTQ_ * 4 + 2];
  __shared__ int st_i, st_j;
  __shared__ int jrow[65];
  const size_t TS = (size_t)SROWS_ * 64;
  const unsigned char* db = dec + (size_t)b * 16 * TS;
  const float* yt = y_t + b * M_;
  float* wv = w_vs + b * N_;

  if (lane == 0) {
    float bc = finf(); int bj = 0;
    for (int c = 0; c < nch; ++c) {
      const float v = partV[b * nch + c];
      const int j = partJ[b * nch + c];
      if (v < bc) { bc = v; bj = j; }
    }
    cost_out[b] = bc;
    st_i = N_ - 1;
    st_j = bj;
    wv[N_ - 1] = yt[bj];
  }
  for (;;) {
    __syncthreads();
    const int i = st_i, j = st_j;
    if (i <= 0) break;
    const int qj = j >> 2;
    int qlo = qj - (BTQ_ - 1);
    if (qlo < 0) qlo = 0;
    const int r = i - lane;
    if (r >= 1) {
      for (int k = 0; k < BTQ_; ++k) {
        const int q = qlo + k;
        win[lane][k] = db[(size_t)(q >> 6) * TS + (size_t)(r + (q & 63)) * 64 + (q & 63)];
      }
      unsigned short run = 0xFFFF;  // stuck sentinel (run extends past window)
      for (int k = 0; k < BTQ_; ++k) {
        const unsigned int byte = win[lane][k];
#pragma unroll
        for (int cs = 0; cs < 4; ++cs) {
          const unsigned int code = (byte >> (2 * cs)) & 3u;
          const int c = 4 * k + cs;
          const unsigned short v =
              (code != 2u) ? (unsigned short)((c << 2) | code) : run;
          tab[lane][c] = v;
          run = v;
        }
      }
    }
    __syncthreads();
    if (lane == 0) {
      const int base = qlo << 2;
      int rr = i, cj = j;
      while (rr >= 1 && (i - rr) < 64) {
        const int l = i - rr;
        const int c = cj - base;
        if (c < 0) break;  // window exhausted; restart super-step
        const unsigned short v = tab[l][c];
        if (v == 0xFFFF) { cj = base - 1; break; }  // 2-run exits window
        const int e = v >> 2;
        const int ce = v & 3;
        cj = base + e - (ce == 0 ? 1 : 0);
        --rr;
        jrow[i - rr] = cj;
      }
      st_i = rr;
      st_j = cj;
    }
    __syncthreads();
    const int cnt = i - st_i;
    if (lane < cnt) wv[i - 1 - lane] = yt[jrow[lane + 1]];
  }
}

// ---------------------------------------------------------------------------
extern "C" void kernel_launch(void* const* d_in, const int* in_sizes, int n_in,
                              void* d_out, int out_size, void* d_ws, size_t ws_size,
                              hipStream_t stream) {
  const float* x = (const float*)d_in[0];
  const float* y = (const float*)d_in[1];
  const float* x_t = (const float*)d_in[2];
  const float* y_t = (const float*)d_in[3];

  float* out_cost = (float*)d_out;      // [B_]
  float* out_wts = out_cost + B_;       // [B_][N_]
  float* out_wvs = out_wts + B_ * N_;   // [B_][N_]

  const size_t decBytes = (size_t)B_ * 16 * SROWS_ * 64;   // 17.8 MB (skewed)
  const size_t x2Bytes = (size_t)B_ * N_ * 4;
  const size_t csBytes = (size_t)B_ * 4 * SROWS_ * 256 * 4;  // 71.2 MB

  char* ws = (char*)d_ws;
  float* Cs = (float*)ws;
  unsigned char* dec = (unsigned char*)(ws + csBytes);
  float* x2 = (float*)(ws + csBytes + decBytes);
  float* carryA = (float*)(ws + csBytes + decBytes + x2Bytes);
  float* carryB = carryA + B_ * N_;
  float* partV = carryB + B_ * N_;
  int* partJ = (int*)(partV + B_ * 4);

  prep_kernel<<<dim3((B_ * N_) / 256), 256, 0, stream>>>(x, x_t, x2, out_wts);

  float* cbuf[2] = {carryA, carryB};
  for (int c = 0; c < 4; ++c) {
    gemm_kernel<<<dim3(4, N_ / 128, B_), 256, 0, stream>>>(x, y, x2, Cs,
                                                           c * 1024);
    const float* cin = cbuf[(c + 1) & 1];
    float* cout = cbuf[c & 1];
    dtw_dp4<<<dim3(4), 1024, 0, stream>>>(Cs, dec, cin, cout, partV, partJ, c,
                                          c > 0 ? 1 : 0);
  }

  backtrack_kernel<<<dim3(B_), 64, 0, stream>>>(dec, partV, partJ, 4, y_t,
                                                out_wvs, out_cost);
}

// Round 7
// 1461.793 us; speedup vs baseline: 2.2004x; 2.2004x over previous
//
#include <hip/hip_runtime.h>

#define B_ 16
#define N_ 1024
#define M_ 4096
#define D_ 64
#define SROWS_ (N_ + 63)        // 1087 valid skewed steps per tile
#define SROWSP_ (SROWS_ + 9)    // padded stride (refill overrun safety)
#define SPAIR_ 544              // step-pairs per tile
#define TSB_ ((size_t)SPAIR_ * 128)  // dec bytes per tile (69632)
#define BTQ_ 96                 // backtrack window quads (384 cells)

__device__ __forceinline__ float finf() { return __builtin_inff(); }

__device__ __forceinline__ float wave_shr1(float x) {
  return __int_as_float(__builtin_amdgcn_update_dpp(
      0, __float_as_int(x), 0x138, 0xF, 0xF, false));
}
__device__ __forceinline__ float rdlane(float v, int l) {
  return __int_as_float(__builtin_amdgcn_readlane(__float_as_int(v), l));
}

// ---------------------------------------------------------------------------
__global__ void prep_kernel(const float* __restrict__ x,
                            const float* __restrict__ x_t,
                            float* __restrict__ x2,
                            float* __restrict__ w_ts_out) {
  int id = blockIdx.x * blockDim.x + threadIdx.x;
  const float4* xr = (const float4*)(x + (size_t)id * D_);
  float s = 0.f;
#pragma unroll
  for (int e = 0; e < D_ / 4; ++e) {
    float4 v = xr[e];
    s += v.x * v.x + v.y * v.y + v.z * v.z + v.w * v.w;
  }
  x2[id] = s;
  w_ts_out[id] = x_t[id];
}

// ---------------------------------------------------------------------------
// GEMM writing C pre-skewed per 256-col tile: Cs[tile][(i+l)*256 + ct], l=ct>>2.
// ---------------------------------------------------------------------------
__global__ __launch_bounds__(256) void gemm_kernel(
    const float* __restrict__ x, const float* __restrict__ y,
    const float* __restrict__ x2, float* __restrict__ Cs, int chunkBase) {
  const int b = blockIdx.z;
  const int tile = blockIdx.x;
  const int lane = threadIdx.x & 63;
  const int wid = threadIdx.x >> 6;
  const int ct = wid * 64 + lane;
  const int j = chunkBase + tile * 256 + ct;
  const int l = ct >> 2;
  float* CsT = Cs + (size_t)(b * 4 + tile) * SROWSP_ * 256;

  const float4* yrow = (const float4*)(y + ((size_t)b * M_ + j) * D_);
  float4 yr[D_ / 4];
#pragma unroll
  for (int e = 0; e < D_ / 4; ++e) yr[e] = yrow[e];
  float y2 = 0.f;
#pragma unroll
  for (int e = 0; e < D_ / 4; ++e)
    y2 += yr[e].x * yr[e].x + yr[e].y * yr[e].y + yr[e].z * yr[e].z + yr[e].w * yr[e].w;

  const int ibeg = blockIdx.y * 128;
  for (int i = ibeg; i < ibeg + 128; ++i) {
    const float4* xr = (const float4*)(x + ((size_t)b * N_ + i) * D_);
    float acc = 0.f;
#pragma unroll
    for (int e = 0; e < D_ / 4; ++e) {
      float4 xv = xr[e];
      acc += xv.x * yr[e].x + xv.y * yr[e].y + xv.z * yr[e].z + xv.w * yr[e].w;
    }
    CsT[(size_t)(i + l) * 256 + ct] = x2[b * N_ + i] + y2 - 2.f * acc;
  }
}

// ---------------------------------------------------------------------------
// Systolic DP, one batch per 256-thread WG (1 wave/SIMD). Wave W owns a
// 256-col tile; lane l owns 4 cols; step s => row i = s - lane. DECOUPLED
// pipeline: full-column (1024-entry) LDS edge buffer per wave pair, producer
// publishes batched (8 rows, lane 63, block end), consumer polls once/block
// with ~8 blocks of slack. dec packed as ushort (2 steps/store).
// ---------------------------------------------------------------------------
__global__ __launch_bounds__(256) void dtw_dp(
    const float* __restrict__ Cs, unsigned char* __restrict__ dec,
    const float* __restrict__ carryIn, float* __restrict__ carryOut,
    float* __restrict__ partV, int* __restrict__ partJ,
    int chunk, int hasCarry) {
  const int b = blockIdx.x;
  const int t = threadIdx.x;
  const int lane = t & 63;
  const int W = t >> 6;

  __shared__ float ring[3][1024];
  __shared__ float cring[1024];
  __shared__ int prog[3];
  __shared__ float redV[4];
  __shared__ int redJ[4];
  volatile int* vProg = prog;

  if (t < 3) prog[t] = -1;
  const float* cIn = carryIn + b * N_;
  if (hasCarry) ((float4*)cring)[t] = ((const float4*)cIn)[t];
  __syncthreads();

  const float INF = finf();
  const float* loadP = Cs + (size_t)(b * 4 + W) * SROWSP_ * 256;
  const int tileG = chunk * 4 + W;
  unsigned short* decP =
      (unsigned short*)(dec + (size_t)(b * 16 + tileG) * TSB_) + lane;
  float* carryB = carryOut + b * N_;
  const int jbase = tileG * 256 + lane * 4;

  float4 cc0 = ((const float4*)(loadP + 0 * 256))[lane];
  float4 cc1 = ((const float4*)(loadP + 1 * 256))[lane];
  float4 cc2 = ((const float4*)(loadP + 2 * 256))[lane];
  float4 cc3 = ((const float4*)(loadP + 3 * 256))[lane];
  float4 cc4 = ((const float4*)(loadP + 4 * 256))[lane];
  float4 cc5 = ((const float4*)(loadP + 5 * 256))[lane];
  float4 cc6 = ((const float4*)(loadP + 6 * 256))[lane];
  float4 cc7 = ((const float4*)(loadP + 7 * 256))[lane];
  loadP += 8 * 256;

  float edgeVec = INF, lvPrev = INF;
  float up0 = 0.f, up1 = 0.f, up2 = 0.f, up3 = 0.f;
  float dpp1 = INF, dpp2 = INF;
  float fin0 = INF, fin1 = INF, fin2 = INF, fin3 = INF;
  float ebuf[8];

#define BLOCKHEAD()                                                           \
  {                                                                           \
    if (W > 0) {                                                              \
      if (sb < N_) {                                                          \
        const int tgt = sb + 7;                                               \
        while (vProg[W - 1] < tgt) {}                                         \
        asm volatile("" ::: "memory");                                        \
        lvPrev = rdlane(edgeVec, 7);                                          \
        edgeVec = ring[W - 1][(sb + lane) & 1023];                            \
      }                                                                       \
    } else if (hasCarry) {                                                    \
      lvPrev = rdlane(edgeVec, 7);                                            \
      if (sb < N_) edgeVec = cring[(sb + lane) & 1023];                       \
    }                                                                         \
  }

#define DPSTEP(KK, CCV, ROW0, FIN)                                            \
  {                                                                           \
    const float lv = rdlane(edgeVec, (KK));                                   \
    const float left = (lane == 0) ? lv : dpp1;                               \
    const float diag = (lane == 0) ? lvPrev : dpp2;                           \
    lvPrev = lv;                                                              \
    float m0 = fminf(up0, left);                                              \
    float bv0 = fminf(diag, m0);                                              \
    unsigned int pk = (diag <= m0) ? 0u : ((up0 <= left) ? 1u : 2u);          \
    if (ROW0) bv0 = (sb + (KK) == lane) ? 0.f : bv0;                          \
    const float D0 = CCV.x + bv0;                                             \
    float m1 = fminf(up1, D0);                                                \
    float bv1 = fminf(up0, m1);                                               \
    pk |= ((up0 <= m1) ? 0u : ((up1 <= D0) ? 1u : 2u)) << 2;                  \
    if (ROW0) bv1 = (sb + (KK) == lane) ? 0.f : bv1;                          \
    const float D1 = CCV.y + bv1;                                             \
    float m2 = fminf(up2, D1);                                                \
    float bv2 = fminf(up1, m2);                                               \
    pk |= ((up1 <= m2) ? 0u : ((up2 <= D1) ? 1u : 2u)) << 4;                  \
    if (ROW0) bv2 = (sb + (KK) == lane) ? 0.f : bv2;                          \
    const float D2 = CCV.z + bv2;                                             \
    float m3 = fminf(up3, D2);                                                \
    float bv3 = fminf(up2, m3);                                               \
    pk |= ((up2 <= m3) ? 0u : ((up3 <= D2) ? 1u : 2u)) << 6;                  \
    if (ROW0) bv3 = (sb + (KK) == lane) ? 0.f : bv3;                          \
    const float D3 = CCV.w + bv3;                                             \
    ebuf[(KK)] = D3;                                                          \
    if ((KK) & 1) {                                                           \
      pk16 |= pk << 8;                                                        \
      decP[((KK) >> 1) * 64] = (unsigned short)pk16;                          \
    } else {                                                                  \
      pk16 = pk;                                                              \
    }                                                                         \
    if (FIN) {                                                                \
      const bool lr = (sb + (KK) == 1023 + lane);                             \
      fin0 = lr ? D0 : fin0; fin1 = lr ? D1 : fin1;                           \
      fin2 = lr ? D2 : fin2; fin3 = lr ? D3 : fin3;                           \
    }                                                                         \
    const float sh = wave_shr1(D3);                                           \
    dpp2 = dpp1; dpp1 = sh;                                                   \
    up0 = D0; up1 = D1; up2 = D2; up3 = D3;                                   \
    CCV = ((const float4*)(loadP + (KK) * 256))[lane];                        \
  }

#define BLOCKEND()                                                            \
  {                                                                           \
    const int r0 = sb - 63;                                                   \
    if (W < 3) {                                                              \
      if (lane == 63 && r0 > -8 && r0 < N_) {                                 \
        _Pragma("unroll") for (int k = 0; k < 8; ++k) {                       \
          const int r = r0 + k;                                               \
          if ((unsigned)r < (unsigned)N_) ring[W][r] = ebuf[k];               \
        }                                                                     \
        __builtin_amdgcn_s_waitcnt(0xC07F);                                   \
        vProg[W] = r0 + 7;                                                    \
      }                                                                       \
    } else if (chunk < 3) {                                                   \
      if (lane == 63 && r0 > -8 && r0 < N_) {                                 \
        _Pragma("unroll") for (int k = 0; k < 8; ++k) {                       \
          const int r = r0 + k;                                               \
          if ((unsigned)r < (unsigned)N_) carryB[r] = ebuf[k];                \
        }                                                                     \
      }                                                                       \
    }                                                                         \
    loadP += 8 * 256;                                                         \
    decP += 256;                                                              \
  }

#define STEP8(R0, FN)                                                         \
  DPSTEP(0, cc0, R0, FN) DPSTEP(1, cc1, R0, FN) DPSTEP(2, cc2, R0, FN)        \
  DPSTEP(3, cc3, R0, FN) DPSTEP(4, cc4, R0, FN) DPSTEP(5, cc5, R0, FN)        \
  DPSTEP(6, cc6, R0, FN) DPSTEP(7, cc7, R0, FN)

  int sb = 0;
  for (; sb < 64; sb += 8) {   // prologue: row-0 selects live
    BLOCKHEAD();
    unsigned int pk16;
    STEP8(1, 0)
    BLOCKEND();
  }
  for (; sb < 1016; sb += 8) { // main
    BLOCKHEAD();
    unsigned int pk16;
    STEP8(0, 0)
    BLOCKEND();
  }
  for (; sb < 1088; sb += 8) { // epilogue: fin captures
    BLOCKHEAD();
    unsigned int pk16;
    STEP8(0, 1)
    BLOCKEND();
  }
#undef DPSTEP
#undef STEP8
#undef BLOCKHEAD
#undef BLOCKEND

  float mv = fin0; int mj = jbase;
  if (fin1 < mv) { mv = fin1; mj = jbase + 1; }
  if (fin2 < mv) { mv = fin2; mj = jbase + 2; }
  if (fin3 < mv) { mv = fin3; mj = jbase + 3; }
#pragma unroll
  for (int off = 32; off > 0; off >>= 1) {
    const float ov = __shfl_down(mv, off);
    const int oj = __shfl_down(mj, off);
    if (ov < mv || (ov == mv && oj < mj)) { mv = ov; mj = oj; }
  }
  if (lane == 0) { redV[W] = mv; redJ[W] = mj; }
  __syncthreads();
  if (t == 0) {
    float bm = redV[0]; int bj = redJ[0];
#pragma unroll
    for (int w = 1; w < 4; ++w)
      if (redV[w] < bm) { bm = redV[w]; bj = redJ[w]; }
    partV[b * 4 + chunk] = bm;
    partJ[b * 4 + chunk] = bj;
  }
}

// ---------------------------------------------------------------------------
// Backtrack over skewed ushort-packed dec. Byte for (row r, quad q):
// tile=q>>6, l=q&63, s=r+l -> tile*TSB + (s>>1)*128 + l*2 + (s&1).
// ---------------------------------------------------------------------------
__global__ __launch_bounds__(64) void backtrack_kernel(
    const unsigned char* __restrict__ dec, const float* __restrict__ partV,
    const int* __restrict__ partJ, int nch, const float* __restrict__ y_t,
    float* __restrict__ w_vs, float* __restrict__ cost_out) {
  const int b = blockIdx.x;
  const int lane = threadIdx.x;
  __shared__ unsigned char win[64][BTQ_ + 4];
  __shared__ unsigned short tab[64][BTQ_ * 4 + 2];
  __shared__ int st_i, st_j;
  __shared__ int jrow[65];
  const unsigned char* db = dec + (size_t)b * 16 * TSB_;
  const float* yt = y_t + b * M_;
  float* wv = w_vs + b * N_;

  if (lane == 0) {
    float bc = finf(); int bj = 0;
    for (int c = 0; c < nch; ++c) {
      const float v = partV[b * nch + c];
      const int j = partJ[b * nch + c];
      if (v < bc) { bc = v; bj = j; }
    }
    cost_out[b] = bc;
    st_i = N_ - 1;
    st_j = bj;
    wv[N_ - 1] = yt[bj];
  }
  for (;;) {
    __syncthreads();
    const int i = st_i, j = st_j;
    if (i <= 0) break;
    const int qj = j >> 2;
    int qlo = qj - (BTQ_ - 1);
    if (qlo < 0) qlo = 0;
    const int r = i - lane;
    if (r >= 1) {
      for (int k = 0; k < BTQ_; ++k) {
        const int q = qlo + k;
        const int l = q & 63;
        const int s = r + l;
        win[lane][k] =
            db[(size_t)(q >> 6) * TSB_ + (size_t)(s >> 1) * 128 + l * 2 + (s & 1)];
      }
      unsigned short run = 0xFFFF;  // stuck sentinel
      for (int k = 0; k < BTQ_; ++k) {
        const unsigned int byte = win[lane][k];
#pragma unroll
        for (int cs = 0; cs < 4; ++cs) {
          const unsigned int code = (byte >> (2 * cs)) & 3u;
          const int c = 4 * k + cs;
          const unsigned short v =
              (code != 2u) ? (unsigned short)((c << 2) | code) : run;
          tab[lane][c] = v;
          run = v;
        }
      }
    }
    __syncthreads();
    if (lane == 0) {
      const int base = qlo << 2;
      int rr = i, cj = j;
      while (rr >= 1 && (i - rr) < 64) {
        const int l = i - rr;
        const int c = cj - base;
        if (c < 0) break;
        const unsigned short v = tab[l][c];
        if (v == 0xFFFF) { cj = base - 1; break; }
        const int e = v >> 2;
        const int ce = v & 3;
        cj = base + e - (ce == 0 ? 1 : 0);
        --rr;
        jrow[i - rr] = cj;
      }
      st_i = rr;
      st_j = cj;
    }
    __syncthreads();
    const int cnt = i - st_i;
    if (lane < cnt) wv[i - 1 - lane] = yt[jrow[lane + 1]];
  }
}

// ---------------------------------------------------------------------------
extern "C" void kernel_launch(void* const* d_in, const int* in_sizes, int n_in,
                              void* d_out, int out_size, void* d_ws, size_t ws_size,
                              hipStream_t stream) {
  const float* x = (const float*)d_in[0];
  const float* y = (const float*)d_in[1];
  const float* x_t = (const float*)d_in[2];
  const float* y_t = (const float*)d_in[3];

  float* out_cost = (float*)d_out;      // [B_]
  float* out_wts = out_cost + B_;       // [B_][N_]
  float* out_wvs = out_wts + B_ * N_;   // [B_][N_]

  const size_t csBytes = (size_t)B_ * 4 * SROWSP_ * 256 * 4;  // ~71.9 MB
  const size_t decBytes = (size_t)B_ * 16 * TSB_;             // ~17.8 MB
  const size_t x2Bytes = (size_t)B_ * N_ * 4;

  char* ws = (char*)d_ws;
  float* Cs = (float*)ws;
  unsigned char* dec = (unsigned char*)(ws + csBytes);
  float* x2 = (float*)(ws + csBytes + decBytes);
  float* carryA = (float*)(ws + csBytes + decBytes + x2Bytes);
  float* carryB = carryA + B_ * N_;
  float* partV = carryB + B_ * N_;
  int* partJ = (int*)(partV + B_ * 4);

  prep_kernel<<<dim3((B_ * N_) / 256), 256, 0, stream>>>(x, x_t, x2, out_wts);

  float* cbuf[2] = {carryA, carryB};
  for (int c = 0; c < 4; ++c) {
    gemm_kernel<<<dim3(4, N_ / 128, B_), 256, 0, stream>>>(x, y, x2, Cs,
                                                           c * 1024);
    const float* cin = cbuf[(c + 1) & 1];
    float* cout = cbuf[c & 1];
    dtw_dp<<<dim3(B_), 256, 0, stream>>>(Cs, dec, cin, cout, partV, partJ, c,
                                         c > 0 ? 1 : 0);
  }

  backtrack_kernel<<<dim3(B_), 64, 0, stream>>>(dec, partV, partJ, 4, y_t,
                                                out_wvs, out_cost);
}